// Round 3
// baseline (466.466 us; speedup 1.0000x reference)
//
#include <hip/hip_runtime.h>
#include <hip/hip_bf16.h>

// FlowLayer: N=8, C=64, H=W=16, EQN=10, GR=4, num=256, unknowns=4*256=1024 per (n,gr).
// A (2560 x 1024) has <=2 entries (+-1 * att) per row, so AtA is a sparse
// graph-Laplacian-like SPD operator. We solve the 32 independent 1024-systems with
// matrix-free PCG (Jacobi + 2x2 coarse deflation of the two near-null constant modes).
// Output dtype: float32 (reference returns f32).

#define NIT 256

// ---------------- squeeze-excite ----------------
__global__ __launch_bounds__(256) void k_se(
    const float* __restrict__ x, const float* __restrict__ sw1,
    const float* __restrict__ sb1, const float* __restrict__ sw2,
    const float* __restrict__ sb2, float* __restrict__ se)
{
  int n = blockIdx.x, t = threadIdx.x;
  __shared__ float part[64*4];
  __shared__ float pooled[64];
  __shared__ float h1[32];
  int c = t >> 2, q = t & 3;
  const float* xp = x + ((n*64 + c)*256) + q*64;
  float s = 0.f;
  #pragma unroll 8
  for (int j = 0; j < 64; ++j) s += xp[j];
  part[c*4+q] = s;
  __syncthreads();
  if (t < 64) pooled[t] = (part[t*4+0]+part[t*4+1]+part[t*4+2]+part[t*4+3]) * (1.f/256.f);
  __syncthreads();
  if (t < 32) {
    float a = sb1[t];
    for (int c2 = 0; c2 < 64; ++c2) a = fmaf(sw1[t*64+c2], pooled[c2], a);
    h1[t] = a >= 0.f ? a : 0.01f*a;
  }
  __syncthreads();
  if (t < 16) {
    float a = sb2[t];
    for (int c2 = 0; c2 < 32; ++c2) a = fmaf(sw2[t*32+c2], h1[c2], a);
    se[n*16+t] = 1.f/(1.f+__expf(-a));
  }
}

// ---------------- 3x3 conv, CIN=64, LDS-staged in 2 halves ----------------
// ACT: 0 none, 1 lrelu, 2 sigmoid
template<int CO_T, int ACT>
__global__ __launch_bounds__(256) void k_conv64(
    const float* __restrict__ xin,   // [8][64][256]
    const float* __restrict__ w,     // [co_total][64][9]
    const float* __restrict__ bias,  // [co_total]
    float* __restrict__ out,         // [8][co_total][256]
    int co_total)
{
  int tiles = co_total / CO_T;
  int b = blockIdx.x;
  int tile = b % tiles, n = b / tiles;
  int co_base = tile * CO_T;
  int t = threadIdx.x;
  int pr = t >> 4, pc = t & 15;
  __shared__ float xs[32*324];          // 32 ch x 18x18 padded, 41.5 KB
  float acc[CO_T];
  #pragma unroll
  for (int co = 0; co < CO_T; ++co) acc[co] = bias[co_base+co];
  const float* xn = xin + n*64*256;
  for (int half = 0; half < 2; ++half) {
    __syncthreads();
    for (int idx = t; idx < 32*324; idx += 256) {
      int ch = idx / 324;
      int rem = idx - ch*324;
      int rr = rem / 18, cc = rem - rr*18;
      int sr = rr - 1, sc = cc - 1;
      float v = 0.f;
      if ((unsigned)sr < 16u && (unsigned)sc < 16u)
        v = xn[(half*32+ch)*256 + sr*16 + sc];
      xs[idx] = v;
    }
    __syncthreads();
    for (int ci = 0; ci < 32; ++ci) {
      const float* xr = xs + ci*324 + pr*18 + pc;
      float x0 = xr[0],  x1 = xr[1],  x2 = xr[2];
      float x3 = xr[18], x4 = xr[19], x5 = xr[20];
      float x6 = xr[36], x7 = xr[37], x8 = xr[38];
      #pragma unroll
      for (int co = 0; co < CO_T; ++co) {
        const float* wp = w + (((size_t)(co_base+co))*64 + half*32 + ci)*9;  // uniform -> s_load
        float a = acc[co];
        a = fmaf(x0,wp[0],a); a = fmaf(x1,wp[1],a); a = fmaf(x2,wp[2],a);
        a = fmaf(x3,wp[3],a); a = fmaf(x4,wp[4],a); a = fmaf(x5,wp[5],a);
        a = fmaf(x6,wp[6],a); a = fmaf(x7,wp[7],a); a = fmaf(x8,wp[8],a);
        acc[co] = a;
      }
    }
  }
  float* ob = out + ((size_t)n*co_total + co_base)*256 + t;
  #pragma unroll
  for (int co = 0; co < CO_T; ++co) {
    float v = acc[co];
    if (ACT == 1) v = v >= 0.f ? v : 0.01f*v;
    if (ACT == 2) v = 1.f/(1.f+__expf(-v));
    ob[co*256] = v;
  }
}

// ---------------- PCG solver: one block per (n,gr) system ----------------
__device__ __forceinline__ float wave_sum(float v){
  #pragma unroll
  for (int m = 1; m < 64; m <<= 1) v += __shfl_xor(v, m, 64);
  return v;
}

__global__ __launch_bounds__(256) void k_cg(
    const float* __restrict__ att, const float* __restrict__ gm,
    float* __restrict__ yout)
{
  int bg = blockIdx.x;
  int n = bg >> 2, g = bg & 3;
  const float* ab = att + ((size_t)n*40 + g*10)*256;
  const float* gb = gm  + ((size_t)n*40 + g*10)*256;
  __shared__ float sA[10][256];   // att^2 per equation per pixel
  __shared__ float tA[10][256];   // att^2 * g
  __shared__ float pl[4][256];    // CG direction p, 4 fields
  __shared__ float redA[4], redB[4], redC[4], redD[4];
  __shared__ float Ec[2];
  int i = threadIdx.x;
  int lane = i & 63, wid = i >> 6;
  float sr[10], tr[10];
  #pragma unroll
  for (int e = 0; e < 10; ++e) {
    float av = ab[e*256+i];
    float s = av*av;
    float tv = s * gb[e*256+i];
    sr[e] = s; tr[e] = tv;
    sA[e][i] = s; tA[e][i] = tv;
  }
  if (i == 255) {   // coarse 2x2 (anchors only; the two sub-systems decouple)
    Ec[0] = sr[0]+sr[2]+sr[4]+sr[7]+sr[9];   // {f0,f2} anchors
    Ec[1] = sr[1]+sr[3]+sr[5]+sr[6]+sr[8];   // {f1,f3} anchors
  }
  __syncthreads();
  int ci = i & 15, ri = i >> 4;
  bool hR = ci < 15, hD = ri < 15, cL = ci > 0, rU = ri > 0;
  bool last = (i == 255);
  int iL = cL ? i-1 : i,  iR = hR ? i+1 : i;
  int iU = rU ? i-16 : i, iD = hD ? i+16 : i;
  float s0L = cL ? sA[0][iL] : 0.f, s2L = cL ? sA[2][iL] : 0.f,
        s4L = cL ? sA[4][iL] : 0.f, s6L = cL ? sA[6][iL] : 0.f,
        s8L = cL ? sA[8][iL] : 0.f;
  float s1U = rU ? sA[1][iU] : 0.f, s3U = rU ? sA[3][iU] : 0.f,
        s5U = rU ? sA[5][iU] : 0.f, s7U = rU ? sA[7][iU] : 0.f,
        s9U = rU ? sA[9][iU] : 0.f;
  float s0i = hR ? sr[0] : 0.f, s2i = hR ? sr[2] : 0.f,
        s4i = hR ? sr[4] : 0.f, s6i = hR ? sr[6] : 0.f, s8i = hR ? sr[8] : 0.f;
  float s1i = hD ? sr[1] : 0.f, s3i = hD ? sr[3] : 0.f,
        s5i = hD ? sr[5] : 0.f, s7i = hD ? sr[7] : 0.f, s9i = hD ? sr[9] : 0.f;
  float d0 = s4i+s4L+s0L+s9i+s9U + (last ? sr[4]+sr[9] : 0.f);
  float d1 = s8i+s8L+s5i+s5U+s1U + (last ? sr[5]+sr[8] : 0.f);
  float d2 = s2i+s0i+s2L+s7i+s7U + (last ? sr[0]+sr[2]+sr[7] : 0.f);
  float d3 = s6i+s6L+s3i+s1i+s3U + (last ? sr[1]+sr[3]+sr[6] : 0.f);
  float tL0 = cL ? tA[0][iL] : 0.f, tL2 = cL ? tA[2][iL] : 0.f,
        tL4 = cL ? tA[4][iL] : 0.f, tL6 = cL ? tA[6][iL] : 0.f,
        tL8 = cL ? tA[8][iL] : 0.f;
  float tU1 = rU ? tA[1][iU] : 0.f, tU3 = rU ? tA[3][iU] : 0.f,
        tU5 = rU ? tA[5][iU] : 0.f, tU7 = rU ? tA[7][iU] : 0.f,
        tU9 = rU ? tA[9][iU] : 0.f;
  float b0 = (hR?tr[4]:0.f) - tL4 - tL0 + (hD?tr[9]:0.f) - tU9 + (last ? tr[4]+tr[9] : 0.f);
  float b1 = (hR?tr[8]:0.f) - tL8 + (hD?tr[5]:0.f) - tU5 - tU1 + (last ? tr[5]+tr[8] : 0.f);
  float b2 = (hR?(tr[2]+tr[0]):0.f) - tL2 + (hD?tr[7]:0.f) - tU7 + (last ? tr[0]+tr[2]+tr[7] : 0.f);
  float b3 = (hR?tr[6]:0.f) - tL6 + (hD?(tr[3]+tr[1]):0.f) - tU3 + (last ? tr[1]+tr[3]+tr[6] : 0.f);
  float di0 = 1.f/(d0+1e-20f), di1 = 1.f/(d1+1e-20f),
        di2 = 1.f/(d2+1e-20f), di3 = 1.f/(d3+1e-20f);
  float ei1 = 1.f/(Ec[0]+1e-20f), ei2 = 1.f/(Ec[1]+1e-20f);
  float x0=0.f,x1=0.f,x2=0.f,x3=0.f;
  float r0=b0, r1=b1, r2=b2, r3=b3;
  // init: combined reduce of (r.D^-1 r, Z^T r)
  float rdr_p = wave_sum(r0*r0*di0 + r1*r1*di1 + r2*r2*di2 + r3*r3*di3);
  float ca = wave_sum(r0+r2), cb = wave_sum(r1+r3);
  if (lane==0){ redB[wid]=rdr_p; redC[wid]=ca; redD[wid]=cb; }
  __syncthreads();
  float rdr = redB[0]+redB[1]+redB[2]+redB[3];
  float cr1 = redC[0]+redC[1]+redC[2]+redC[3];
  float cr2 = redD[0]+redD[1]+redD[2]+redD[3];
  float rz = rdr + cr1*cr1*ei1 + cr2*cr2*ei2;
  float cc1 = cr1*ei1, cc2 = cr2*ei2;
  pl[0][i] = di0*r0 + cc1; pl[1][i] = di1*r1 + cc2;
  pl[2][i] = di2*r2 + cc1; pl[3][i] = di3*r3 + cc2;
  __syncthreads();
  for (int it = 0; it < NIT; ++it) {
    float p0=pl[0][i], p1=pl[1][i], p2=pl[2][i], p3=pl[3][i];
    float p0R=pl[0][iR], p0L=pl[0][iL], p0D=pl[0][iD], p0U=pl[0][iU];
    float p1R=pl[1][iR], p1L=pl[1][iL], p1D=pl[1][iD], p1U=pl[1][iU];
    float p2R=pl[2][iR], p2L=pl[2][iL], p2D=pl[2][iD], p2U=pl[2][iU];
    float p3R=pl[3][iR], p3L=pl[3][iL], p3D=pl[3][iD], p3U=pl[3][iU];
    float q0 = d0*p0 - s4i*p0R - s4L*p0L - s0L*p2L - s9i*p0D - s9U*p0U;
    float q1 = d1*p1 - s8i*p1R - s8L*p1L - s5i*p1D - s5U*p1U - s1U*p3U;
    float q2 = d2*p2 - s2i*p2R - s2L*p2L - s7i*p2D - s7U*p2U - s0i*p0R;
    float q3 = d3*p3 - s6i*p3R - s6L*p3L - s3i*p3D - s3U*p3U - s1i*p1D;
    float pq_p = wave_sum(p0*q0+p1*q1+p2*q2+p3*q3);
    if (lane==0) redA[wid]=pq_p;
    __syncthreads();
    float pq = redA[0]+redA[1]+redA[2]+redA[3];
    float alpha = pq > 1e-35f ? rz/pq : 0.f;
    x0 = fmaf(alpha,p0,x0); x1 = fmaf(alpha,p1,x1);
    x2 = fmaf(alpha,p2,x2); x3 = fmaf(alpha,p3,x3);
    r0 = fmaf(-alpha,q0,r0); r1 = fmaf(-alpha,q1,r1);
    r2 = fmaf(-alpha,q2,r2); r3 = fmaf(-alpha,q3,r3);
    float rdr2 = wave_sum(r0*r0*di0 + r1*r1*di1 + r2*r2*di2 + r3*r3*di3);
    float ca2 = wave_sum(r0+r2), cb2 = wave_sum(r1+r3);
    if (lane==0){ redB[wid]=rdr2; redC[wid]=ca2; redD[wid]=cb2; }
    __syncthreads();
    float rdrT = redB[0]+redB[1]+redB[2]+redB[3];
    float c1T  = redC[0]+redC[1]+redC[2]+redC[3];
    float c2T  = redD[0]+redD[1]+redD[2]+redD[3];
    float rz2 = rdrT + c1T*c1T*ei1 + c2T*c2T*ei2;
    float beta = rz > 1e-35f ? rz2/rz : 0.f;
    rz = rz2;
    float z0 = di0*r0 + c1T*ei1, z1 = di1*r1 + c2T*ei2;
    float z2 = di2*r2 + c1T*ei1, z3 = di3*r3 + c2T*ei2;
    pl[0][i] = fmaf(beta,p0,z0); pl[1][i] = fmaf(beta,p1,z1);
    pl[2][i] = fmaf(beta,p2,z2); pl[3][i] = fmaf(beta,p3,z3);
    __syncthreads();
  }
  float* yo = yout + ((size_t)n*16 + g*4)*256 + i;
  yo[0] = x0; yo[256] = x1; yo[512] = x2; yo[768] = x3;
}

// ---------------- GroupNorm + SE + final 3x3 conv 16->128, f32 out ----------------
__global__ __launch_bounds__(256) void k_out(
    const float* __restrict__ y, const float* __restrict__ insw,
    const float* __restrict__ insb, const float* __restrict__ sev,
    const float* __restrict__ pw, const float* __restrict__ pb,
    float* __restrict__ out)
{
  int b = blockIdx.x;
  int cot = b & 7, n = b >> 3;
  int t = threadIdx.x;
  int pr = t >> 4, pc = t & 15;
  __shared__ float ys[16*324];
  __shared__ float redA[4], redB[4];
  const float* yb = y + (size_t)n*16*256;
  float s = 0.f, s2 = 0.f;
  #pragma unroll
  for (int c = 0; c < 16; ++c) {
    float v = yb[c*256 + t];
    s += v; s2 = fmaf(v, v, s2);
  }
  for (int idx = t; idx < 16*324; idx += 256) {
    int ch = idx / 324;
    int rem = idx - ch*324;
    int rr = rem / 18, cc = rem - rr*18;
    int sr = rr-1, sc = cc-1;
    float v = 0.f;
    if ((unsigned)sr < 16u && (unsigned)sc < 16u) v = yb[ch*256 + sr*16 + sc];
    ys[idx] = v;
  }
  int lane = t & 63, wid = t >> 6;
  #pragma unroll
  for (int m = 1; m < 64; m <<= 1) { s += __shfl_xor(s, m, 64); s2 += __shfl_xor(s2, m, 64); }
  if (lane == 0) { redA[wid] = s; redB[wid] = s2; }
  __syncthreads();
  float S  = redA[0]+redA[1]+redA[2]+redA[3];
  float SS = redB[0]+redB[1]+redB[2]+redB[3];
  float mu = S * (1.f/4096.f);
  float var = SS * (1.f/4096.f) - mu*mu;
  float rstd = rsqrtf(var + 1e-5f);
  for (int idx = t; idx < 16*324; idx += 256) {
    int ch = idx / 324;
    int rem = idx - ch*324;
    int rr = rem / 18, cc = rem - rr*18;
    int sr = rr-1, sc = cc-1;
    if ((unsigned)sr < 16u && (unsigned)sc < 16u) {
      float sef = sev[n*16+ch];
      float m = rstd * insw[ch] * sef;
      float a = (insb[ch] - mu*rstd*insw[ch]) * sef;
      ys[idx] = fmaf(ys[idx], m, a);
    }
  }
  __syncthreads();
  float acc[16];
  #pragma unroll
  for (int co = 0; co < 16; ++co) acc[co] = pb[cot*16+co];
  for (int ci = 0; ci < 16; ++ci) {
    const float* xr = ys + ci*324 + pr*18 + pc;
    float x0 = xr[0],  x1 = xr[1],  x2 = xr[2];
    float x3 = xr[18], x4 = xr[19], x5 = xr[20];
    float x6 = xr[36], x7 = xr[37], x8 = xr[38];
    #pragma unroll
    for (int co = 0; co < 16; ++co) {
      const float* wp = pw + (((size_t)(cot*16+co))*16 + ci)*9;
      float a = acc[co];
      a = fmaf(x0,wp[0],a); a = fmaf(x1,wp[1],a); a = fmaf(x2,wp[2],a);
      a = fmaf(x3,wp[3],a); a = fmaf(x4,wp[4],a); a = fmaf(x5,wp[5],a);
      a = fmaf(x6,wp[6],a); a = fmaf(x7,wp[7],a); a = fmaf(x8,wp[8],a);
      acc[co] = a;
    }
  }
  float* ob = out + ((size_t)n*128 + cot*16)*256 + t;
  #pragma unroll
  for (int co = 0; co < 16; ++co)
    ob[co*256] = acc[co];
}

extern "C" void kernel_launch(void* const* d_in, const int* in_sizes, int n_in,
                              void* d_out, int out_size, void* d_ws, size_t ws_size,
                              hipStream_t stream) {
  const float* x    = (const float*)d_in[0];
  // d_in[1] = 'a' (structure hardcoded analytically)
  const float* gw1  = (const float*)d_in[2];
  const float* gb1  = (const float*)d_in[3];
  const float* gw2  = (const float*)d_in[4];
  const float* gb2  = (const float*)d_in[5];
  const float* aw1  = (const float*)d_in[6];
  const float* ab1  = (const float*)d_in[7];
  const float* aw2  = (const float*)d_in[8];
  const float* ab2  = (const float*)d_in[9];
  const float* sw1  = (const float*)d_in[10];
  const float* sb1  = (const float*)d_in[11];
  const float* sw2  = (const float*)d_in[12];
  const float* sb2  = (const float*)d_in[13];
  const float* insw = (const float*)d_in[14];
  const float* insb = (const float*)d_in[15];
  const float* pw   = (const float*)d_in[16];
  const float* pb   = (const float*)d_in[17];
  float* ws = (float*)d_ws;
  float* g1   = ws;             // [8][64][256]
  float* a1   = ws + 131072;    // [8][64][256]
  float* gmat = ws + 262144;    // [8][40][256]
  float* attb = ws + 344064;    // [8][40][256]
  float* sev  = ws + 425984;    // [8][16]
  float* ybuf = ws + 426112;    // [8][16][256]
  float* out  = (float*)d_out;

  k_se<<<dim3(8), dim3(256), 0, stream>>>(x, sw1, sb1, sw2, sb2, sev);
  k_conv64<8,1><<<dim3(64), dim3(256), 0, stream>>>(x, gw1, gb1, g1, 64);
  k_conv64<8,1><<<dim3(64), dim3(256), 0, stream>>>(x, aw1, ab1, a1, 64);
  k_conv64<10,0><<<dim3(32), dim3(256), 0, stream>>>(g1, gw2, gb2, gmat, 40);
  k_conv64<10,2><<<dim3(32), dim3(256), 0, stream>>>(a1, aw2, ab2, attb, 40);
  k_cg<<<dim3(32), dim3(256), 0, stream>>>(attb, gmat, ybuf);
  k_out<<<dim3(64), dim3(256), 0, stream>>>(ybuf, insw, insb, sev, pw, pb, out);
}

// Round 5
// 333.198 us; speedup vs baseline: 1.4000x; 1.4000x over previous
//
#include <hip/hip_runtime.h>
#include <hip/hip_bf16.h>

// FlowLayer: N=8, C=64, H=W=16, EQN=10, GR=4, num=256, unknowns=4*256=1024 per (n,gr).
// AtA is a sparse graph-Laplacian SPD stencil. 32 independent systems solved with
// matrix-free PCG (Jacobi + 2x2 coarse deflation), ONE WAVE per system:
// 4 pixels/lane, state in registers, dots via shfl_xor butterflies (no barriers),
// neighbor exchange via LDS p-mirror (wave-synchronous).
// NOTE: pixel row stride is 16 (W), so U/D neighbors are base +/- 16 (NOT 64).

#define NIT 128

// ---------------- squeeze-excite ----------------
__global__ __launch_bounds__(256) void k_se(
    const float* __restrict__ x, const float* __restrict__ sw1,
    const float* __restrict__ sb1, const float* __restrict__ sw2,
    const float* __restrict__ sb2, float* __restrict__ se)
{
  int n = blockIdx.x, t = threadIdx.x;
  __shared__ float part[64*4];
  __shared__ float pooled[64];
  __shared__ float h1[32];
  int c = t >> 2, q = t & 3;
  const float* xp = x + ((n*64 + c)*256) + q*64;
  float s = 0.f;
  #pragma unroll 8
  for (int j = 0; j < 64; ++j) s += xp[j];
  part[c*4+q] = s;
  __syncthreads();
  if (t < 64) pooled[t] = (part[t*4+0]+part[t*4+1]+part[t*4+2]+part[t*4+3]) * (1.f/256.f);
  __syncthreads();
  if (t < 32) {
    float a = sb1[t];
    for (int c2 = 0; c2 < 64; ++c2) a = fmaf(sw1[t*64+c2], pooled[c2], a);
    h1[t] = a >= 0.f ? a : 0.01f*a;
  }
  __syncthreads();
  if (t < 16) {
    float a = sb2[t];
    for (int c2 = 0; c2 < 32; ++c2) a = fmaf(sw2[t*32+c2], h1[c2], a);
    se[n*16+t] = 1.f/(1.f+__expf(-a));
  }
}

// ---------------- 3x3 conv, CIN=64, LDS-staged in 2 halves ----------------
template<int CO_T, int ACT>
__global__ __launch_bounds__(256) void k_conv64(
    const float* __restrict__ xin,   // [8][64][256]
    const float* __restrict__ w,     // [co_total][64][9]
    const float* __restrict__ bias,  // [co_total]
    float* __restrict__ out,         // [8][co_total][256]
    int co_total)
{
  int tiles = co_total / CO_T;
  int b = blockIdx.x;
  int tile = b % tiles, n = b / tiles;
  int co_base = tile * CO_T;
  int t = threadIdx.x;
  int pr = t >> 4, pc = t & 15;
  __shared__ float xs[32*324];
  float acc[CO_T];
  #pragma unroll
  for (int co = 0; co < CO_T; ++co) acc[co] = bias[co_base+co];
  const float* xn = xin + n*64*256;
  for (int half = 0; half < 2; ++half) {
    __syncthreads();
    for (int idx = t; idx < 32*324; idx += 256) {
      int ch = idx / 324;
      int rem = idx - ch*324;
      int rr = rem / 18, cc = rem - rr*18;
      int sr = rr - 1, sc = cc - 1;
      float v = 0.f;
      if ((unsigned)sr < 16u && (unsigned)sc < 16u)
        v = xn[(half*32+ch)*256 + sr*16 + sc];
      xs[idx] = v;
    }
    __syncthreads();
    for (int ci = 0; ci < 32; ++ci) {
      const float* xr = xs + ci*324 + pr*18 + pc;
      float x0 = xr[0],  x1 = xr[1],  x2 = xr[2];
      float x3 = xr[18], x4 = xr[19], x5 = xr[20];
      float x6 = xr[36], x7 = xr[37], x8 = xr[38];
      #pragma unroll
      for (int co = 0; co < CO_T; ++co) {
        const float* wp = w + (((size_t)(co_base+co))*64 + half*32 + ci)*9;
        float a = acc[co];
        a = fmaf(x0,wp[0],a); a = fmaf(x1,wp[1],a); a = fmaf(x2,wp[2],a);
        a = fmaf(x3,wp[3],a); a = fmaf(x4,wp[4],a); a = fmaf(x5,wp[5],a);
        a = fmaf(x6,wp[6],a); a = fmaf(x7,wp[7],a); a = fmaf(x8,wp[8],a);
        acc[co] = a;
      }
    }
  }
  float* ob = out + ((size_t)n*co_total + co_base)*256 + t;
  #pragma unroll
  for (int co = 0; co < CO_T; ++co) {
    float v = acc[co];
    if (ACT == 1) v = v >= 0.f ? v : 0.01f*v;
    if (ACT == 2) v = 1.f/(1.f+__expf(-v));
    ob[co*256] = v;
  }
}

// ---------------- PCG solver: ONE WAVE per (n,gr) system ----------------
__device__ __forceinline__ float wave_sum(float v){
  #pragma unroll
  for (int m = 1; m < 64; m <<= 1) v += __shfl_xor(v, m, 64);
  return v;
}

__global__ __launch_bounds__(64, 1) void k_cg(
    const float* __restrict__ att, const float* __restrict__ gm,
    float* __restrict__ yout)
{
  int bg = blockIdx.x;
  int n = bg >> 2, g = bg & 3;
  const float* ab = att + ((size_t)n*40 + g*10)*256;
  const float* gb = gm  + ((size_t)n*40 + g*10)*256;
  __shared__ float sbuf[10][256];
  __shared__ float tbuf[10][256];
  __shared__ float pl[4][256];
  int l = threadIdx.x;          // lane 0..63
  int base = l*4;               // first pixel of this lane
  int rI = l >> 2;              // row 0..15
  int c0 = (l & 3)*4;           // col of j=0
  bool rU4 = (rI > 0), hD4 = (rI < 15);
  int iL0 = (base > 0) ? base-1 : 0;        // clamped L addr (gated)
  int iR3 = (base < 252) ? base+4 : 252;    // clamped R addr (gated)
  int iUc = rU4 ? base-16 : base;           // clamped U addr: row stride 16 (gated)
  int iDc = hD4 ? base+16 : base;           // clamped D addr: row stride 16 (gated)

  // ---- load att^2 (sr) and att^2*g (tr) for 4 pixels x 10 eq; mirror to LDS ----
  float sr[10][4], tr[10][4];
  #pragma unroll
  for (int e = 0; e < 10; ++e) {
    float4 av = *(const float4*)(ab + e*256 + base);
    float4 gv = *(const float4*)(gb + e*256 + base);
    sr[e][0]=av.x*av.x; sr[e][1]=av.y*av.y; sr[e][2]=av.z*av.z; sr[e][3]=av.w*av.w;
    tr[e][0]=sr[e][0]*gv.x; tr[e][1]=sr[e][1]*gv.y; tr[e][2]=sr[e][2]*gv.z; tr[e][3]=sr[e][3]*gv.w;
    *(float4*)(&sbuf[e][base]) = make_float4(sr[e][0],sr[e][1],sr[e][2],sr[e][3]);
    *(float4*)(&tbuf[e][base]) = make_float4(tr[e][0],tr[e][1],tr[e][2],tr[e][3]);
  }
  __syncthreads();

  // ---- shifted coefficient fetch (L-shift for col eqs, U-shift for row eqs) ----
  const int eL[5] = {0,2,4,6,8};
  const int eU[5] = {1,3,5,7,9};
  float sLs[5][4], tLs[5][4], sUs[5][4], tUs[5][4];
  float gU = rU4 ? 1.f : 0.f;
  #pragma unroll
  for (int k = 0; k < 5; ++k) {
    int e = eL[k];
    sLs[k][0] = (c0 > 0) ? sbuf[e][iL0] : 0.f;
    tLs[k][0] = (c0 > 0) ? tbuf[e][iL0] : 0.f;
    #pragma unroll
    for (int j = 1; j < 4; ++j) { sLs[k][j] = sr[e][j-1]; tLs[k][j] = tr[e][j-1]; }
  }
  #pragma unroll
  for (int k = 0; k < 5; ++k) {
    int e = eU[k];
    float4 su = *(const float4*)(&sbuf[e][iUc]);
    float4 tu = *(const float4*)(&tbuf[e][iUc]);
    sUs[k][0]=su.x*gU; sUs[k][1]=su.y*gU; sUs[k][2]=su.z*gU; sUs[k][3]=su.w*gU;
    tUs[k][0]=tu.x*gU; tUs[k][1]=tu.y*gU; tUs[k][2]=tu.z*gU; tUs[k][3]=tu.w*gU;
  }

  // ---- per-pixel stencil coefficients + diag + RHS ----
  float k0R[4],k0L[4],k0X[4],k0D[4],k0U[4], d0[4],di0[4], b0[4];
  float k1R[4],k1L[4],k1D[4],k1U[4],k1X[4], d1[4],di1[4], b1[4];
  float k2R[4],k2L[4],k2D[4],k2U[4],k2X[4], d2[4],di2[4], b2[4];
  float k3R[4],k3L[4],k3D[4],k3U[4],k3X[4], d3[4],di3[4], b3[4];
  #pragma unroll
  for (int j = 0; j < 4; ++j) {
    bool hR = (c0 + j) < 15;
    bool hD = hD4;
    bool last = (l == 63) && (j == 3);
    k0R[j] = hR ? sr[4][j] : 0.f;  k0L[j] = sLs[2][j];  k0X[j] = sLs[0][j];
    k0D[j] = hD ? sr[9][j] : 0.f;  k0U[j] = sUs[4][j];
    k1R[j] = hR ? sr[8][j] : 0.f;  k1L[j] = sLs[4][j];
    k1D[j] = hD ? sr[5][j] : 0.f;  k1U[j] = sUs[2][j];  k1X[j] = sUs[0][j];
    k2R[j] = hR ? sr[2][j] : 0.f;  k2L[j] = sLs[1][j];
    k2D[j] = hD ? sr[7][j] : 0.f;  k2U[j] = sUs[3][j];  k2X[j] = hR ? sr[0][j] : 0.f;
    k3R[j] = hR ? sr[6][j] : 0.f;  k3L[j] = sLs[3][j];
    k3D[j] = hD ? sr[3][j] : 0.f;  k3U[j] = sUs[1][j];  k3X[j] = hD ? sr[1][j] : 0.f;
    d0[j] = k0R[j]+k0L[j]+k0X[j]+k0D[j]+k0U[j] + (last ? sr[4][j]+sr[9][j] : 0.f);
    d1[j] = k1R[j]+k1L[j]+k1D[j]+k1U[j]+k1X[j] + (last ? sr[5][j]+sr[8][j] : 0.f);
    d2[j] = k2R[j]+k2L[j]+k2D[j]+k2U[j]+k2X[j] + (last ? sr[0][j]+sr[2][j]+sr[7][j] : 0.f);
    d3[j] = k3R[j]+k3L[j]+k3D[j]+k3U[j]+k3X[j] + (last ? sr[1][j]+sr[3][j]+sr[6][j] : 0.f);
    b0[j] = (hR?tr[4][j]:0.f) - tLs[2][j] - tLs[0][j] + (hD?tr[9][j]:0.f) - tUs[4][j]
          + (last ? tr[4][j]+tr[9][j] : 0.f);
    b1[j] = (hR?tr[8][j]:0.f) - tLs[4][j] + (hD?tr[5][j]:0.f) - tUs[2][j] - tUs[0][j]
          + (last ? tr[5][j]+tr[8][j] : 0.f);
    b2[j] = (hR?(tr[2][j]+tr[0][j]):0.f) - tLs[1][j] + (hD?tr[7][j]:0.f) - tUs[3][j]
          + (last ? tr[0][j]+tr[2][j]+tr[7][j] : 0.f);
    b3[j] = (hR?tr[6][j]:0.f) - tLs[3][j] + (hD?(tr[3][j]+tr[1][j]):0.f) - tUs[1][j]
          + (last ? tr[1][j]+tr[3][j]+tr[6][j] : 0.f);
    di0[j] = 1.f/(d0[j]+1e-20f); di1[j] = 1.f/(d1[j]+1e-20f);
    di2[j] = 1.f/(d2[j]+1e-20f); di3[j] = 1.f/(d3[j]+1e-20f);
  }

  // ---- coarse 2x2 deflation (anchor sums at pixel 255, lane 63 j=3) ----
  float vA = sr[0][3]+sr[2][3]+sr[4][3]+sr[7][3]+sr[9][3];
  float vB = sr[1][3]+sr[3][3]+sr[5][3]+sr[6][3]+sr[8][3];
  float ei1 = 1.f/(__shfl(vA, 63, 64)+1e-20f);
  float ei2 = 1.f/(__shfl(vB, 63, 64)+1e-20f);

  // ---- CG init ----
  float x0[4],x1[4],x2[4],x3[4], r0[4],r1[4],r2[4],r3[4], p0[4],p1[4],p2[4],p3[4];
  float rdr_p = 0.f, ca_p = 0.f, cb_p = 0.f;
  #pragma unroll
  for (int j = 0; j < 4; ++j) {
    x0[j]=0.f; x1[j]=0.f; x2[j]=0.f; x3[j]=0.f;
    r0[j]=b0[j]; r1[j]=b1[j]; r2[j]=b2[j]; r3[j]=b3[j];
    rdr_p += r0[j]*r0[j]*di0[j] + r1[j]*r1[j]*di1[j] + r2[j]*r2[j]*di2[j] + r3[j]*r3[j]*di3[j];
    ca_p += r0[j]+r2[j]; cb_p += r1[j]+r3[j];
  }
  float rdr = wave_sum(rdr_p), ca = wave_sum(ca_p), cb = wave_sum(cb_p);
  float rz = rdr + ca*ca*ei1 + cb*cb*ei2;
  float cc1 = ca*ei1, cc2 = cb*ei2;
  #pragma unroll
  for (int j = 0; j < 4; ++j) {
    p0[j] = di0[j]*r0[j] + cc1; p1[j] = di1[j]*r1[j] + cc2;
    p2[j] = di2[j]*r2[j] + cc1; p3[j] = di3[j]*r3[j] + cc2;
  }
  *(float4*)(&pl[0][base]) = make_float4(p0[0],p0[1],p0[2],p0[3]);
  *(float4*)(&pl[1][base]) = make_float4(p1[0],p1[1],p1[2],p1[3]);
  *(float4*)(&pl[2][base]) = make_float4(p2[0],p2[1],p2[2],p2[3]);
  *(float4*)(&pl[3][base]) = make_float4(p3[0],p3[1],p3[2],p3[3]);
  __syncthreads();

  // ---- main loop: wave-synchronous ----
  for (int it = 0; it < NIT; ++it) {
    float nR0 = pl[0][iR3], nR1 = pl[1][iR3], nR2 = pl[2][iR3], nR3 = pl[3][iR3];
    float nL0 = pl[0][iL0], nL1 = pl[1][iL0], nL2 = pl[2][iL0], nL3 = pl[3][iL0];
    float4 u0 = *(const float4*)(&pl[0][iUc]);
    float4 u1 = *(const float4*)(&pl[1][iUc]);
    float4 u2 = *(const float4*)(&pl[2][iUc]);
    float4 u3 = *(const float4*)(&pl[3][iUc]);
    float4 w0 = *(const float4*)(&pl[0][iDc]);
    float4 w1 = *(const float4*)(&pl[1][iDc]);
    float4 w2 = *(const float4*)(&pl[2][iDc]);
    float4 w3 = *(const float4*)(&pl[3][iDc]);
    float pU0[4]={u0.x,u0.y,u0.z,u0.w}, pU1[4]={u1.x,u1.y,u1.z,u1.w};
    float pU2[4]={u2.x,u2.y,u2.z,u2.w}, pU3[4]={u3.x,u3.y,u3.z,u3.w};
    float pD0[4]={w0.x,w0.y,w0.z,w0.w}, pD1[4]={w1.x,w1.y,w1.z,w1.w};
    float pD2[4]={w2.x,w2.y,w2.z,w2.w}, pD3[4]={w3.x,w3.y,w3.z,w3.w};
    float q0[4],q1[4],q2[4],q3[4];
    float pq_p = 0.f;
    #pragma unroll
    for (int j = 0; j < 4; ++j) {
      float p0R = (j<3)? p0[j+1] : nR0;  float p0L = (j>0)? p0[j-1] : nL0;
      float p1R = (j<3)? p1[j+1] : nR1;  float p1L = (j>0)? p1[j-1] : nL1;
      float p2R = (j<3)? p2[j+1] : nR2;  float p2L = (j>0)? p2[j-1] : nL2;
      float p3R = (j<3)? p3[j+1] : nR3;  float p3L = (j>0)? p3[j-1] : nL3;
      q0[j] = d0[j]*p0[j] - k0R[j]*p0R - k0L[j]*p0L - k0X[j]*p2L - k0D[j]*pD0[j] - k0U[j]*pU0[j];
      q1[j] = d1[j]*p1[j] - k1R[j]*p1R - k1L[j]*p1L - k1D[j]*pD1[j] - k1U[j]*pU1[j] - k1X[j]*pU3[j];
      q2[j] = d2[j]*p2[j] - k2R[j]*p2R - k2L[j]*p2L - k2D[j]*pD2[j] - k2U[j]*pU2[j] - k2X[j]*p0R;
      q3[j] = d3[j]*p3[j] - k3R[j]*p3R - k3L[j]*p3L - k3D[j]*pD3[j] - k3U[j]*pU3[j] - k3X[j]*pD1[j];
      pq_p += p0[j]*q0[j] + p1[j]*q1[j] + p2[j]*q2[j] + p3[j]*q3[j];
    }
    float pq = wave_sum(pq_p);
    float alpha = pq > 1e-35f ? rz/pq : 0.f;
    float rdr2_p = 0.f, ca2_p = 0.f, cb2_p = 0.f;
    #pragma unroll
    for (int j = 0; j < 4; ++j) {
      x0[j] = fmaf(alpha,p0[j],x0[j]); x1[j] = fmaf(alpha,p1[j],x1[j]);
      x2[j] = fmaf(alpha,p2[j],x2[j]); x3[j] = fmaf(alpha,p3[j],x3[j]);
      r0[j] = fmaf(-alpha,q0[j],r0[j]); r1[j] = fmaf(-alpha,q1[j],r1[j]);
      r2[j] = fmaf(-alpha,q2[j],r2[j]); r3[j] = fmaf(-alpha,q3[j],r3[j]);
      rdr2_p += r0[j]*r0[j]*di0[j] + r1[j]*r1[j]*di1[j] + r2[j]*r2[j]*di2[j] + r3[j]*r3[j]*di3[j];
      ca2_p += r0[j]+r2[j]; cb2_p += r1[j]+r3[j];
    }
    float rdrT = wave_sum(rdr2_p), c1T = wave_sum(ca2_p), c2T = wave_sum(cb2_p);
    float rz2 = rdrT + c1T*c1T*ei1 + c2T*c2T*ei2;
    float beta = rz > 1e-35f ? rz2/rz : 0.f;
    rz = rz2;
    float z1c = c1T*ei1, z2c = c2T*ei2;
    #pragma unroll
    for (int j = 0; j < 4; ++j) {
      p0[j] = fmaf(beta,p0[j], di0[j]*r0[j] + z1c);
      p1[j] = fmaf(beta,p1[j], di1[j]*r1[j] + z2c);
      p2[j] = fmaf(beta,p2[j], di2[j]*r2[j] + z1c);
      p3[j] = fmaf(beta,p3[j], di3[j]*r3[j] + z2c);
    }
    *(float4*)(&pl[0][base]) = make_float4(p0[0],p0[1],p0[2],p0[3]);
    *(float4*)(&pl[1][base]) = make_float4(p1[0],p1[1],p1[2],p1[3]);
    *(float4*)(&pl[2][base]) = make_float4(p2[0],p2[1],p2[2],p2[3]);
    *(float4*)(&pl[3][base]) = make_float4(p3[0],p3[1],p3[2],p3[3]);
    __syncthreads();
  }
  float* yo = yout + ((size_t)n*16 + g*4)*256 + base;
  *(float4*)(yo)       = make_float4(x0[0],x0[1],x0[2],x0[3]);
  *(float4*)(yo + 256) = make_float4(x1[0],x1[1],x1[2],x1[3]);
  *(float4*)(yo + 512) = make_float4(x2[0],x2[1],x2[2],x2[3]);
  *(float4*)(yo + 768) = make_float4(x3[0],x3[1],x3[2],x3[3]);
}

// ---------------- GroupNorm + SE + final 3x3 conv 16->128, f32 out ----------------
__global__ __launch_bounds__(256) void k_out(
    const float* __restrict__ y, const float* __restrict__ insw,
    const float* __restrict__ insb, const float* __restrict__ sev,
    const float* __restrict__ pw, const float* __restrict__ pb,
    float* __restrict__ out)
{
  int b = blockIdx.x;
  int cot = b & 7, n = b >> 3;
  int t = threadIdx.x;
  int pr = t >> 4, pc = t & 15;
  __shared__ float ys[16*324];
  __shared__ float redA[4], redB[4];
  const float* yb = y + (size_t)n*16*256;
  float s = 0.f, s2 = 0.f;
  #pragma unroll
  for (int c = 0; c < 16; ++c) {
    float v = yb[c*256 + t];
    s += v; s2 = fmaf(v, v, s2);
  }
  for (int idx = t; idx < 16*324; idx += 256) {
    int ch = idx / 324;
    int rem = idx - ch*324;
    int rr = rem / 18, cc = rem - rr*18;
    int sr = rr-1, sc = cc-1;
    float v = 0.f;
    if ((unsigned)sr < 16u && (unsigned)sc < 16u) v = yb[ch*256 + sr*16 + sc];
    ys[idx] = v;
  }
  int lane = t & 63, wid = t >> 6;
  #pragma unroll
  for (int m = 1; m < 64; m <<= 1) { s += __shfl_xor(s, m, 64); s2 += __shfl_xor(s2, m, 64); }
  if (lane == 0) { redA[wid] = s; redB[wid] = s2; }
  __syncthreads();
  float S  = redA[0]+redA[1]+redA[2]+redA[3];
  float SS = redB[0]+redB[1]+redB[2]+redB[3];
  float mu = S * (1.f/4096.f);
  float var = SS * (1.f/4096.f) - mu*mu;
  float rstd = rsqrtf(var + 1e-5f);
  for (int idx = t; idx < 16*324; idx += 256) {
    int ch = idx / 324;
    int rem = idx - ch*324;
    int rr = rem / 18, cc = rem - rr*18;
    int sr = rr-1, sc = cc-1;
    if ((unsigned)sr < 16u && (unsigned)sc < 16u) {
      float sef = sev[n*16+ch];
      float m = rstd * insw[ch] * sef;
      float a = (insb[ch] - mu*rstd*insw[ch]) * sef;
      ys[idx] = fmaf(ys[idx], m, a);
    }
  }
  __syncthreads();
  float acc[16];
  #pragma unroll
  for (int co = 0; co < 16; ++co) acc[co] = pb[cot*16+co];
  for (int ci = 0; ci < 16; ++ci) {
    const float* xr = ys + ci*324 + pr*18 + pc;
    float x0 = xr[0],  x1 = xr[1],  x2 = xr[2];
    float x3 = xr[18], x4 = xr[19], x5 = xr[20];
    float x6 = xr[36], x7 = xr[37], x8 = xr[38];
    #pragma unroll
    for (int co = 0; co < 16; ++co) {
      const float* wp = pw + (((size_t)(cot*16+co))*16 + ci)*9;
      float a = acc[co];
      a = fmaf(x0,wp[0],a); a = fmaf(x1,wp[1],a); a = fmaf(x2,wp[2],a);
      a = fmaf(x3,wp[3],a); a = fmaf(x4,wp[4],a); a = fmaf(x5,wp[5],a);
      a = fmaf(x6,wp[6],a); a = fmaf(x7,wp[7],a); a = fmaf(x8,wp[8],a);
      acc[co] = a;
    }
  }
  float* ob = out + ((size_t)n*128 + cot*16)*256 + t;
  #pragma unroll
  for (int co = 0; co < 16; ++co)
    ob[co*256] = acc[co];
}

extern "C" void kernel_launch(void* const* d_in, const int* in_sizes, int n_in,
                              void* d_out, int out_size, void* d_ws, size_t ws_size,
                              hipStream_t stream) {
  const float* x    = (const float*)d_in[0];
  // d_in[1] = 'a' (structure hardcoded analytically)
  const float* gw1  = (const float*)d_in[2];
  const float* gb1  = (const float*)d_in[3];
  const float* gw2  = (const float*)d_in[4];
  const float* gb2  = (const float*)d_in[5];
  const float* aw1  = (const float*)d_in[6];
  const float* ab1  = (const float*)d_in[7];
  const float* aw2  = (const float*)d_in[8];
  const float* ab2  = (const float*)d_in[9];
  const float* sw1  = (const float*)d_in[10];
  const float* sb1  = (const float*)d_in[11];
  const float* sw2  = (const float*)d_in[12];
  const float* sb2  = (const float*)d_in[13];
  const float* insw = (const float*)d_in[14];
  const float* insb = (const float*)d_in[15];
  const float* pw   = (const float*)d_in[16];
  const float* pb   = (const float*)d_in[17];
  float* ws = (float*)d_ws;
  float* g1   = ws;             // [8][64][256]
  float* a1   = ws + 131072;    // [8][64][256]
  float* gmat = ws + 262144;    // [8][40][256]
  float* attb = ws + 344064;    // [8][40][256]
  float* sev  = ws + 425984;    // [8][16]
  float* ybuf = ws + 426112;    // [8][16][256]
  float* out  = (float*)d_out;

  k_se<<<dim3(8), dim3(256), 0, stream>>>(x, sw1, sb1, sw2, sb2, sev);
  k_conv64<8,1><<<dim3(64), dim3(256), 0, stream>>>(x, gw1, gb1, g1, 64);
  k_conv64<8,1><<<dim3(64), dim3(256), 0, stream>>>(x, aw1, ab1, a1, 64);
  k_conv64<10,0><<<dim3(32), dim3(256), 0, stream>>>(g1, gw2, gb2, gmat, 40);
  k_conv64<10,2><<<dim3(32), dim3(256), 0, stream>>>(a1, aw2, ab2, attb, 40);
  k_cg<<<dim3(32), dim3(64), 0, stream>>>(attb, gmat, ybuf);
  k_out<<<dim3(64), dim3(256), 0, stream>>>(ybuf, insw, insb, sev, pw, pb, out);
}

// Round 6
// 159.214 us; speedup vs baseline: 2.9298x; 2.0928x over previous
//
#include <hip/hip_runtime.h>
#include <hip/hip_bf16.h>

// FlowLayer: N=8, C=64, H=W=16, EQN=10, GR=4, num=256, unknowns=4*256=1024 per (n,gr).
// AtA is a sparse graph-Laplacian SPD stencil. 32 independent systems solved with
// matrix-free PCG (Jacobi + 2x2 coarse deflation), ONE WAVE per system.
// Pixel row stride is 16 (W): U/D neighbors are base +/- 16.
// Branch pairs (g/a) fused into single kernels for parallelism + fewer launches.

#define NIT 64

// ---------------- squeeze-excite ----------------
__global__ __launch_bounds__(256) void k_se(
    const float* __restrict__ x, const float* __restrict__ sw1,
    const float* __restrict__ sb1, const float* __restrict__ sw2,
    const float* __restrict__ sb2, float* __restrict__ se)
{
  int n = blockIdx.x, t = threadIdx.x;
  __shared__ float part[64*4];
  __shared__ float pooled[64];
  __shared__ float h1[32];
  int c = t >> 2, q = t & 3;
  const float* xp = x + ((n*64 + c)*256) + q*64;
  float s = 0.f;
  #pragma unroll 8
  for (int j = 0; j < 64; ++j) s += xp[j];
  part[c*4+q] = s;
  __syncthreads();
  if (t < 64) pooled[t] = (part[t*4+0]+part[t*4+1]+part[t*4+2]+part[t*4+3]) * (1.f/256.f);
  __syncthreads();
  if (t < 32) {
    float a = sb1[t];
    for (int c2 = 0; c2 < 64; ++c2) a = fmaf(sw1[t*64+c2], pooled[c2], a);
    h1[t] = a >= 0.f ? a : 0.01f*a;
  }
  __syncthreads();
  if (t < 16) {
    float a = sb2[t];
    for (int c2 = 0; c2 < 32; ++c2) a = fmaf(sw2[t*32+c2], h1[c2], a);
    se[n*16+t] = 1.f/(1.f+__expf(-a));
  }
}

// ---------------- fused 3x3 conv stage 1: x -> {g1, a1}, CIN=64, CO=64, lrelu ----
template<int CO_T>
__global__ __launch_bounds__(256) void k_conv1(
    const float* __restrict__ x,
    const float* __restrict__ gw1, const float* __restrict__ gb1,
    const float* __restrict__ aw1, const float* __restrict__ ab1,
    float* __restrict__ g1, float* __restrict__ a1)
{
  const int tiles = 64 / CO_T;
  int b = blockIdx.x;                 // [n][br][tile]
  int tile = b % tiles; int rem = b / tiles;
  int br = rem & 1;     int n = rem >> 1;
  const float* w    = br ? aw1 : gw1;
  const float* bias = br ? ab1 : gb1;
  float* outp       = br ? a1  : g1;
  int co_base = tile * CO_T;
  int t = threadIdx.x;
  int pr = t >> 4, pc = t & 15;
  __shared__ float xs[32*324];
  float acc[CO_T];
  #pragma unroll
  for (int co = 0; co < CO_T; ++co) acc[co] = bias[co_base+co];
  const float* xn = x + n*64*256;
  for (int half = 0; half < 2; ++half) {
    __syncthreads();
    for (int idx = t; idx < 32*324; idx += 256) {
      int ch = idx / 324;
      int rm = idx - ch*324;
      int rr = rm / 18, cc = rm - rr*18;
      int sr = rr - 1, sc = cc - 1;
      float v = 0.f;
      if ((unsigned)sr < 16u && (unsigned)sc < 16u)
        v = xn[(half*32+ch)*256 + sr*16 + sc];
      xs[idx] = v;
    }
    __syncthreads();
    for (int ci = 0; ci < 32; ++ci) {
      const float* xr = xs + ci*324 + pr*18 + pc;
      float x0 = xr[0],  x1 = xr[1],  x2 = xr[2];
      float x3 = xr[18], x4 = xr[19], x5 = xr[20];
      float x6 = xr[36], x7 = xr[37], x8 = xr[38];
      #pragma unroll
      for (int co = 0; co < CO_T; ++co) {
        const float* wp = w + (((size_t)(co_base+co))*64 + half*32 + ci)*9;
        float a = acc[co];
        a = fmaf(x0,wp[0],a); a = fmaf(x1,wp[1],a); a = fmaf(x2,wp[2],a);
        a = fmaf(x3,wp[3],a); a = fmaf(x4,wp[4],a); a = fmaf(x5,wp[5],a);
        a = fmaf(x6,wp[6],a); a = fmaf(x7,wp[7],a); a = fmaf(x8,wp[8],a);
        acc[co] = a;
      }
    }
  }
  float* ob = outp + ((size_t)n*64 + co_base)*256 + t;
  #pragma unroll
  for (int co = 0; co < CO_T; ++co) {
    float v = acc[co];
    ob[co*256] = v >= 0.f ? v : 0.01f*v;   // lrelu both branches
  }
}

// ---------------- fused 3x3 conv stage 2: {g1,a1} -> {gmat, attb}, CO=40 ----
template<int CO_T>
__global__ __launch_bounds__(256) void k_conv2(
    const float* __restrict__ g1, const float* __restrict__ a1,
    const float* __restrict__ gw2, const float* __restrict__ gb2,
    const float* __restrict__ aw2, const float* __restrict__ ab2,
    float* __restrict__ gmat, float* __restrict__ attb)
{
  const int tiles = 40 / CO_T;
  int b = blockIdx.x;                 // [n][br][tile]
  int tile = b % tiles; int rem = b / tiles;
  int br = rem & 1;     int n = rem >> 1;
  const float* xin  = br ? a1  : g1;
  const float* w    = br ? aw2 : gw2;
  const float* bias = br ? ab2 : gb2;
  float* outp       = br ? attb : gmat;
  int co_base = tile * CO_T;
  int t = threadIdx.x;
  int pr = t >> 4, pc = t & 15;
  __shared__ float xs[32*324];
  float acc[CO_T];
  #pragma unroll
  for (int co = 0; co < CO_T; ++co) acc[co] = bias[co_base+co];
  const float* xn = xin + n*64*256;
  for (int half = 0; half < 2; ++half) {
    __syncthreads();
    for (int idx = t; idx < 32*324; idx += 256) {
      int ch = idx / 324;
      int rm = idx - ch*324;
      int rr = rm / 18, cc = rm - rr*18;
      int sr = rr - 1, sc = cc - 1;
      float v = 0.f;
      if ((unsigned)sr < 16u && (unsigned)sc < 16u)
        v = xn[(half*32+ch)*256 + sr*16 + sc];
      xs[idx] = v;
    }
    __syncthreads();
    for (int ci = 0; ci < 32; ++ci) {
      const float* xr = xs + ci*324 + pr*18 + pc;
      float x0 = xr[0],  x1 = xr[1],  x2 = xr[2];
      float x3 = xr[18], x4 = xr[19], x5 = xr[20];
      float x6 = xr[36], x7 = xr[37], x8 = xr[38];
      #pragma unroll
      for (int co = 0; co < CO_T; ++co) {
        const float* wp = w + (((size_t)(co_base+co))*64 + half*32 + ci)*9;
        float a = acc[co];
        a = fmaf(x0,wp[0],a); a = fmaf(x1,wp[1],a); a = fmaf(x2,wp[2],a);
        a = fmaf(x3,wp[3],a); a = fmaf(x4,wp[4],a); a = fmaf(x5,wp[5],a);
        a = fmaf(x6,wp[6],a); a = fmaf(x7,wp[7],a); a = fmaf(x8,wp[8],a);
        acc[co] = a;
      }
    }
  }
  float* ob = outp + ((size_t)n*40 + co_base)*256 + t;
  #pragma unroll
  for (int co = 0; co < CO_T; ++co) {
    float v = acc[co];
    if (br) v = 1.f/(1.f+__expf(-v));     // sigmoid for attention branch
    ob[co*256] = v;
  }
}

// ---------------- PCG solver: ONE WAVE per (n,gr) system ----------------
__device__ __forceinline__ float wave_sum(float v){
  #pragma unroll
  for (int m = 1; m < 64; m <<= 1) v += __shfl_xor(v, m, 64);
  return v;
}

__global__ __launch_bounds__(64, 1) void k_cg(
    const float* __restrict__ att, const float* __restrict__ gm,
    float* __restrict__ yout)
{
  int bg = blockIdx.x;
  int n = bg >> 2, g = bg & 3;
  const float* ab = att + ((size_t)n*40 + g*10)*256;
  const float* gb = gm  + ((size_t)n*40 + g*10)*256;
  __shared__ float sbuf[10][256];
  __shared__ float tbuf[10][256];
  __shared__ float pl[4][256];
  int l = threadIdx.x;          // lane 0..63
  int base = l*4;               // first pixel of this lane
  int rI = l >> 2;              // row 0..15
  int c0 = (l & 3)*4;           // col of j=0
  bool rU4 = (rI > 0), hD4 = (rI < 15);
  int iL0 = (base > 0) ? base-1 : 0;        // clamped L addr (gated)
  int iR3 = (base < 252) ? base+4 : 252;    // clamped R addr (gated)
  int iUc = rU4 ? base-16 : base;           // clamped U addr: row stride 16
  int iDc = hD4 ? base+16 : base;           // clamped D addr: row stride 16

  float sr[10][4], tr[10][4];
  #pragma unroll
  for (int e = 0; e < 10; ++e) {
    float4 av = *(const float4*)(ab + e*256 + base);
    float4 gv = *(const float4*)(gb + e*256 + base);
    sr[e][0]=av.x*av.x; sr[e][1]=av.y*av.y; sr[e][2]=av.z*av.z; sr[e][3]=av.w*av.w;
    tr[e][0]=sr[e][0]*gv.x; tr[e][1]=sr[e][1]*gv.y; tr[e][2]=sr[e][2]*gv.z; tr[e][3]=sr[e][3]*gv.w;
    *(float4*)(&sbuf[e][base]) = make_float4(sr[e][0],sr[e][1],sr[e][2],sr[e][3]);
    *(float4*)(&tbuf[e][base]) = make_float4(tr[e][0],tr[e][1],tr[e][2],tr[e][3]);
  }
  __syncthreads();

  const int eL[5] = {0,2,4,6,8};
  const int eU[5] = {1,3,5,7,9};
  float sLs[5][4], tLs[5][4], sUs[5][4], tUs[5][4];
  float gU = rU4 ? 1.f : 0.f;
  #pragma unroll
  for (int k = 0; k < 5; ++k) {
    int e = eL[k];
    sLs[k][0] = (c0 > 0) ? sbuf[e][iL0] : 0.f;
    tLs[k][0] = (c0 > 0) ? tbuf[e][iL0] : 0.f;
    #pragma unroll
    for (int j = 1; j < 4; ++j) { sLs[k][j] = sr[e][j-1]; tLs[k][j] = tr[e][j-1]; }
  }
  #pragma unroll
  for (int k = 0; k < 5; ++k) {
    int e = eU[k];
    float4 su = *(const float4*)(&sbuf[e][iUc]);
    float4 tu = *(const float4*)(&tbuf[e][iUc]);
    sUs[k][0]=su.x*gU; sUs[k][1]=su.y*gU; sUs[k][2]=su.z*gU; sUs[k][3]=su.w*gU;
    tUs[k][0]=tu.x*gU; tUs[k][1]=tu.y*gU; tUs[k][2]=tu.z*gU; tUs[k][3]=tu.w*gU;
  }

  float k0R[4],k0L[4],k0X[4],k0D[4],k0U[4], d0[4],di0[4], b0[4];
  float k1R[4],k1L[4],k1D[4],k1U[4],k1X[4], d1[4],di1[4], b1[4];
  float k2R[4],k2L[4],k2D[4],k2U[4],k2X[4], d2[4],di2[4], b2[4];
  float k3R[4],k3L[4],k3D[4],k3U[4],k3X[4], d3[4],di3[4], b3[4];
  #pragma unroll
  for (int j = 0; j < 4; ++j) {
    bool hR = (c0 + j) < 15;
    bool hD = hD4;
    bool last = (l == 63) && (j == 3);
    k0R[j] = hR ? sr[4][j] : 0.f;  k0L[j] = sLs[2][j];  k0X[j] = sLs[0][j];
    k0D[j] = hD ? sr[9][j] : 0.f;  k0U[j] = sUs[4][j];
    k1R[j] = hR ? sr[8][j] : 0.f;  k1L[j] = sLs[4][j];
    k1D[j] = hD ? sr[5][j] : 0.f;  k1U[j] = sUs[2][j];  k1X[j] = sUs[0][j];
    k2R[j] = hR ? sr[2][j] : 0.f;  k2L[j] = sLs[1][j];
    k2D[j] = hD ? sr[7][j] : 0.f;  k2U[j] = sUs[3][j];  k2X[j] = hR ? sr[0][j] : 0.f;
    k3R[j] = hR ? sr[6][j] : 0.f;  k3L[j] = sLs[3][j];
    k3D[j] = hD ? sr[3][j] : 0.f;  k3U[j] = sUs[1][j];  k3X[j] = hD ? sr[1][j] : 0.f;
    d0[j] = k0R[j]+k0L[j]+k0X[j]+k0D[j]+k0U[j] + (last ? sr[4][j]+sr[9][j] : 0.f);
    d1[j] = k1R[j]+k1L[j]+k1D[j]+k1U[j]+k1X[j] + (last ? sr[5][j]+sr[8][j] : 0.f);
    d2[j] = k2R[j]+k2L[j]+k2D[j]+k2U[j]+k2X[j] + (last ? sr[0][j]+sr[2][j]+sr[7][j] : 0.f);
    d3[j] = k3R[j]+k3L[j]+k3D[j]+k3U[j]+k3X[j] + (last ? sr[1][j]+sr[3][j]+sr[6][j] : 0.f);
    b0[j] = (hR?tr[4][j]:0.f) - tLs[2][j] - tLs[0][j] + (hD?tr[9][j]:0.f) - tUs[4][j]
          + (last ? tr[4][j]+tr[9][j] : 0.f);
    b1[j] = (hR?tr[8][j]:0.f) - tLs[4][j] + (hD?tr[5][j]:0.f) - tUs[2][j] - tUs[0][j]
          + (last ? tr[5][j]+tr[8][j] : 0.f);
    b2[j] = (hR?(tr[2][j]+tr[0][j]):0.f) - tLs[1][j] + (hD?tr[7][j]:0.f) - tUs[3][j]
          + (last ? tr[0][j]+tr[2][j]+tr[7][j] : 0.f);
    b3[j] = (hR?tr[6][j]:0.f) - tLs[3][j] + (hD?(tr[3][j]+tr[1][j]):0.f) - tUs[1][j]
          + (last ? tr[1][j]+tr[3][j]+tr[6][j] : 0.f);
    di0[j] = 1.f/(d0[j]+1e-20f); di1[j] = 1.f/(d1[j]+1e-20f);
    di2[j] = 1.f/(d2[j]+1e-20f); di3[j] = 1.f/(d3[j]+1e-20f);
  }

  float vA = sr[0][3]+sr[2][3]+sr[4][3]+sr[7][3]+sr[9][3];
  float vB = sr[1][3]+sr[3][3]+sr[5][3]+sr[6][3]+sr[8][3];
  float ei1 = 1.f/(__shfl(vA, 63, 64)+1e-20f);
  float ei2 = 1.f/(__shfl(vB, 63, 64)+1e-20f);

  float x0[4],x1[4],x2[4],x3[4], r0[4],r1[4],r2[4],r3[4], p0[4],p1[4],p2[4],p3[4];
  float rdr_p = 0.f, ca_p = 0.f, cb_p = 0.f;
  #pragma unroll
  for (int j = 0; j < 4; ++j) {
    x0[j]=0.f; x1[j]=0.f; x2[j]=0.f; x3[j]=0.f;
    r0[j]=b0[j]; r1[j]=b1[j]; r2[j]=b2[j]; r3[j]=b3[j];
    rdr_p += r0[j]*r0[j]*di0[j] + r1[j]*r1[j]*di1[j] + r2[j]*r2[j]*di2[j] + r3[j]*r3[j]*di3[j];
    ca_p += r0[j]+r2[j]; cb_p += r1[j]+r3[j];
  }
  float rdr = wave_sum(rdr_p), ca = wave_sum(ca_p), cb = wave_sum(cb_p);
  float rz = rdr + ca*ca*ei1 + cb*cb*ei2;
  float cc1 = ca*ei1, cc2 = cb*ei2;
  #pragma unroll
  for (int j = 0; j < 4; ++j) {
    p0[j] = di0[j]*r0[j] + cc1; p1[j] = di1[j]*r1[j] + cc2;
    p2[j] = di2[j]*r2[j] + cc1; p3[j] = di3[j]*r3[j] + cc2;
  }
  *(float4*)(&pl[0][base]) = make_float4(p0[0],p0[1],p0[2],p0[3]);
  *(float4*)(&pl[1][base]) = make_float4(p1[0],p1[1],p1[2],p1[3]);
  *(float4*)(&pl[2][base]) = make_float4(p2[0],p2[1],p2[2],p2[3]);
  *(float4*)(&pl[3][base]) = make_float4(p3[0],p3[1],p3[2],p3[3]);
  __syncthreads();

  for (int it = 0; it < NIT; ++it) {
    float nR0 = pl[0][iR3], nR1 = pl[1][iR3], nR2 = pl[2][iR3], nR3 = pl[3][iR3];
    float nL0 = pl[0][iL0], nL1 = pl[1][iL0], nL2 = pl[2][iL0], nL3 = pl[3][iL0];
    float4 u0 = *(const float4*)(&pl[0][iUc]);
    float4 u1 = *(const float4*)(&pl[1][iUc]);
    float4 u2 = *(const float4*)(&pl[2][iUc]);
    float4 u3 = *(const float4*)(&pl[3][iUc]);
    float4 w0 = *(const float4*)(&pl[0][iDc]);
    float4 w1 = *(const float4*)(&pl[1][iDc]);
    float4 w2 = *(const float4*)(&pl[2][iDc]);
    float4 w3 = *(const float4*)(&pl[3][iDc]);
    float pU0[4]={u0.x,u0.y,u0.z,u0.w}, pU1[4]={u1.x,u1.y,u1.z,u1.w};
    float pU2[4]={u2.x,u2.y,u2.z,u2.w}, pU3[4]={u3.x,u3.y,u3.z,u3.w};
    float pD0[4]={w0.x,w0.y,w0.z,w0.w}, pD1[4]={w1.x,w1.y,w1.z,w1.w};
    float pD2[4]={w2.x,w2.y,w2.z,w2.w}, pD3[4]={w3.x,w3.y,w3.z,w3.w};
    float q0[4],q1[4],q2[4],q3[4];
    float pq_p = 0.f;
    #pragma unroll
    for (int j = 0; j < 4; ++j) {
      float p0R = (j<3)? p0[j+1] : nR0;  float p0L = (j>0)? p0[j-1] : nL0;
      float p1R = (j<3)? p1[j+1] : nR1;  float p1L = (j>0)? p1[j-1] : nL1;
      float p2R = (j<3)? p2[j+1] : nR2;  float p2L = (j>0)? p2[j-1] : nL2;
      float p3R = (j<3)? p3[j+1] : nR3;  float p3L = (j>0)? p3[j-1] : nL3;
      q0[j] = d0[j]*p0[j] - k0R[j]*p0R - k0L[j]*p0L - k0X[j]*p2L - k0D[j]*pD0[j] - k0U[j]*pU0[j];
      q1[j] = d1[j]*p1[j] - k1R[j]*p1R - k1L[j]*p1L - k1D[j]*pD1[j] - k1U[j]*pU1[j] - k1X[j]*pU3[j];
      q2[j] = d2[j]*p2[j] - k2R[j]*p2R - k2L[j]*p2L - k2D[j]*pD2[j] - k2U[j]*pU2[j] - k2X[j]*p0R;
      q3[j] = d3[j]*p3[j] - k3R[j]*p3R - k3L[j]*p3L - k3D[j]*pD3[j] - k3U[j]*pU3[j] - k3X[j]*pD1[j];
      pq_p += p0[j]*q0[j] + p1[j]*q1[j] + p2[j]*q2[j] + p3[j]*q3[j];
    }
    float pq = wave_sum(pq_p);
    float alpha = pq > 1e-35f ? rz/pq : 0.f;
    float rdr2_p = 0.f, ca2_p = 0.f, cb2_p = 0.f;
    #pragma unroll
    for (int j = 0; j < 4; ++j) {
      x0[j] = fmaf(alpha,p0[j],x0[j]); x1[j] = fmaf(alpha,p1[j],x1[j]);
      x2[j] = fmaf(alpha,p2[j],x2[j]); x3[j] = fmaf(alpha,p3[j],x3[j]);
      r0[j] = fmaf(-alpha,q0[j],r0[j]); r1[j] = fmaf(-alpha,q1[j],r1[j]);
      r2[j] = fmaf(-alpha,q2[j],r2[j]); r3[j] = fmaf(-alpha,q3[j],r3[j]);
      rdr2_p += r0[j]*r0[j]*di0[j] + r1[j]*r1[j]*di1[j] + r2[j]*r2[j]*di2[j] + r3[j]*r3[j]*di3[j];
      ca2_p += r0[j]+r2[j]; cb2_p += r1[j]+r3[j];
    }
    float rdrT = wave_sum(rdr2_p), c1T = wave_sum(ca2_p), c2T = wave_sum(cb2_p);
    float rz2 = rdrT + c1T*c1T*ei1 + c2T*c2T*ei2;
    float beta = rz > 1e-35f ? rz2/rz : 0.f;
    rz = rz2;
    float z1c = c1T*ei1, z2c = c2T*ei2;
    #pragma unroll
    for (int j = 0; j < 4; ++j) {
      p0[j] = fmaf(beta,p0[j], di0[j]*r0[j] + z1c);
      p1[j] = fmaf(beta,p1[j], di1[j]*r1[j] + z2c);
      p2[j] = fmaf(beta,p2[j], di2[j]*r2[j] + z1c);
      p3[j] = fmaf(beta,p3[j], di3[j]*r3[j] + z2c);
    }
    *(float4*)(&pl[0][base]) = make_float4(p0[0],p0[1],p0[2],p0[3]);
    *(float4*)(&pl[1][base]) = make_float4(p1[0],p1[1],p1[2],p1[3]);
    *(float4*)(&pl[2][base]) = make_float4(p2[0],p2[1],p2[2],p2[3]);
    *(float4*)(&pl[3][base]) = make_float4(p3[0],p3[1],p3[2],p3[3]);
    __syncthreads();
  }
  float* yo = yout + ((size_t)n*16 + g*4)*256 + base;
  *(float4*)(yo)       = make_float4(x0[0],x0[1],x0[2],x0[3]);
  *(float4*)(yo + 256) = make_float4(x1[0],x1[1],x1[2],x1[3]);
  *(float4*)(yo + 512) = make_float4(x2[0],x2[1],x2[2],x2[3]);
  *(float4*)(yo + 768) = make_float4(x3[0],x3[1],x3[2],x3[3]);
}

// ---------------- GroupNorm + SE + final 3x3 conv 16->128, f32 out ----------------
template<int CO_T>
__global__ __launch_bounds__(256) void k_out(
    const float* __restrict__ y, const float* __restrict__ insw,
    const float* __restrict__ insb, const float* __restrict__ sev,
    const float* __restrict__ pw, const float* __restrict__ pb,
    float* __restrict__ out)
{
  const int tiles = 128 / CO_T;
  int b = blockIdx.x;
  int cot = b % tiles, n = b / tiles;
  int co_base = cot * CO_T;
  int t = threadIdx.x;
  int pr = t >> 4, pc = t & 15;
  __shared__ float ys[16*324];
  __shared__ float redA[4], redB[4];
  const float* yb = y + (size_t)n*16*256;
  float s = 0.f, s2 = 0.f;
  #pragma unroll
  for (int c = 0; c < 16; ++c) {
    float v = yb[c*256 + t];
    s += v; s2 = fmaf(v, v, s2);
  }
  for (int idx = t; idx < 16*324; idx += 256) {
    int ch = idx / 324;
    int rem = idx - ch*324;
    int rr = rem / 18, cc = rem - rr*18;
    int sr = rr-1, sc = cc-1;
    float v = 0.f;
    if ((unsigned)sr < 16u && (unsigned)sc < 16u) v = yb[ch*256 + sr*16 + sc];
    ys[idx] = v;
  }
  int lane = t & 63, wid = t >> 6;
  #pragma unroll
  for (int m = 1; m < 64; m <<= 1) { s += __shfl_xor(s, m, 64); s2 += __shfl_xor(s2, m, 64); }
  if (lane == 0) { redA[wid] = s; redB[wid] = s2; }
  __syncthreads();
  float S  = redA[0]+redA[1]+redA[2]+redA[3];
  float SS = redB[0]+redB[1]+redB[2]+redB[3];
  float mu = S * (1.f/4096.f);
  float var = SS * (1.f/4096.f) - mu*mu;
  float rstd = rsqrtf(var + 1e-5f);
  for (int idx = t; idx < 16*324; idx += 256) {
    int ch = idx / 324;
    int rem = idx - ch*324;
    int rr = rem / 18, cc = rem - rr*18;
    int sr = rr-1, sc = cc-1;
    if ((unsigned)sr < 16u && (unsigned)sc < 16u) {
      float sef = sev[n*16+ch];
      float m = rstd * insw[ch] * sef;
      float a = (insb[ch] - mu*rstd*insw[ch]) * sef;
      ys[idx] = fmaf(ys[idx], m, a);
    }
  }
  __syncthreads();
  float acc[CO_T];
  #pragma unroll
  for (int co = 0; co < CO_T; ++co) acc[co] = pb[co_base+co];
  for (int ci = 0; ci < 16; ++ci) {
    const float* xr = ys + ci*324 + pr*18 + pc;
    float x0 = xr[0],  x1 = xr[1],  x2 = xr[2];
    float x3 = xr[18], x4 = xr[19], x5 = xr[20];
    float x6 = xr[36], x7 = xr[37], x8 = xr[38];
    #pragma unroll
    for (int co = 0; co < CO_T; ++co) {
      const float* wp = pw + (((size_t)(co_base+co))*16 + ci)*9;
      float a = acc[co];
      a = fmaf(x0,wp[0],a); a = fmaf(x1,wp[1],a); a = fmaf(x2,wp[2],a);
      a = fmaf(x3,wp[3],a); a = fmaf(x4,wp[4],a); a = fmaf(x5,wp[5],a);
      a = fmaf(x6,wp[6],a); a = fmaf(x7,wp[7],a); a = fmaf(x8,wp[8],a);
      acc[co] = a;
    }
  }
  float* ob = out + ((size_t)n*128 + co_base)*256 + t;
  #pragma unroll
  for (int co = 0; co < CO_T; ++co)
    ob[co*256] = acc[co];
}

extern "C" void kernel_launch(void* const* d_in, const int* in_sizes, int n_in,
                              void* d_out, int out_size, void* d_ws, size_t ws_size,
                              hipStream_t stream) {
  const float* x    = (const float*)d_in[0];
  // d_in[1] = 'a' (structure hardcoded analytically)
  const float* gw1  = (const float*)d_in[2];
  const float* gb1  = (const float*)d_in[3];
  const float* gw2  = (const float*)d_in[4];
  const float* gb2  = (const float*)d_in[5];
  const float* aw1  = (const float*)d_in[6];
  const float* ab1  = (const float*)d_in[7];
  const float* aw2  = (const float*)d_in[8];
  const float* ab2  = (const float*)d_in[9];
  const float* sw1  = (const float*)d_in[10];
  const float* sb1  = (const float*)d_in[11];
  const float* sw2  = (const float*)d_in[12];
  const float* sb2  = (const float*)d_in[13];
  const float* insw = (const float*)d_in[14];
  const float* insb = (const float*)d_in[15];
  const float* pw   = (const float*)d_in[16];
  const float* pb   = (const float*)d_in[17];
  float* ws = (float*)d_ws;
  float* g1   = ws;             // [8][64][256]
  float* a1   = ws + 131072;    // [8][64][256]
  float* gmat = ws + 262144;    // [8][40][256]
  float* attb = ws + 344064;    // [8][40][256]
  float* sev  = ws + 425984;    // [8][16]
  float* ybuf = ws + 426112;    // [8][16][256]
  float* out  = (float*)d_out;

  k_se<<<dim3(8), dim3(256), 0, stream>>>(x, sw1, sb1, sw2, sb2, sev);
  k_conv1<4><<<dim3(256), dim3(256), 0, stream>>>(x, gw1, gb1, aw1, ab1, g1, a1);
  k_conv2<5><<<dim3(128), dim3(256), 0, stream>>>(g1, a1, gw2, gb2, aw2, ab2, gmat, attb);
  k_cg<<<dim3(32), dim3(64), 0, stream>>>(attb, gmat, ybuf);
  k_out<8><<<dim3(128), dim3(256), 0, stream>>>(ybuf, insw, insb, sev, pw, pb, out);
}